// Round 1
// 1275.862 us; speedup vs baseline: 1.0404x; 1.0404x over previous
//
#include <hip/hip_runtime.h>
#include <math.h>

// Problem constants (fixed by reference setup_inputs):
//   x:    (B=16, C=64, H=512, W=512) float32
//   mask: (B=16, 1,    H=512, W=512) int32 (0/1)
//   out:  (B=16, C=64) float32
#define BB 16
#define CC 64
#define HW (512 * 512)        // 262144 spatial elements per (b,c) plane
#define SS 8                  // spatial splits per plane
#define CH (HW / SS)          // 32768 elements per chunk
#define TPB 256
#define VEC_ITERS (CH / 4 / TPB)   // 32 float4 iterations per thread
#define GROUPS (BB * HW / 4)       // 1,048,576 float4-groups (packed bytes)
#define PM_PER_B (HW / 4)          // 65536 packed bytes per batch
#define PM_CH (CH / 4)             // 8192 packed bytes per chunk

typedef float f4 __attribute__((ext_vector_type(4)));

// Kernel 0: pack mask int32 0/1 -> one nibble (in a byte) per float4-group.
// 16.8 MB read, 1 MB written. Packed mask is L2-resident on every XCD
// afterwards, killing the full-rate int32 mask side-stream of the main pass.
__global__ __launch_bounds__(TPB) void mask_pack(
    const int4* __restrict__ mask, unsigned char* __restrict__ pm) {
  const int g = blockIdx.x * TPB + threadIdx.x;
  const int4 m = mask[g];
  pm[g] = (unsigned char)((m.x != 0) | ((m.y != 0) << 1) |
                          ((m.z != 0) << 2) | ((m.w != 0) << 3));
}

// Kernel 1: each block reduces one (b, c, s) chunk to a single partial max.
// x loads are non-temporal (zero reuse -> don't evict packed mask from L2).
// Grid ordering: c fastest -> 64 consecutive blocks share one packed-mask
// chunk (8 KB, trivially cache-resident).
__global__ __launch_bounds__(TPB) void maskpool_partial(
    const float* __restrict__ x,
    const unsigned char* __restrict__ pm,
    float* __restrict__ partial) {
  const int blk = blockIdx.x;
  const int b = blk / (SS * CC);
  const int rem = blk % (SS * CC);
  const int s = rem / CC;
  const int c = rem % CC;

  const f4* __restrict__ xp = reinterpret_cast<const f4*>(
      x + (size_t)(b * CC + c) * HW + (size_t)s * CH);
  const unsigned char* __restrict__ mp =
      pm + (size_t)b * PM_PER_B + (size_t)s * PM_CH;

  const int t = threadIdx.x;
  float acc = -INFINITY;

#pragma unroll 8
  for (int i = 0; i < VEC_ITERS; ++i) {
    const int idx = t + i * TPB;
    const f4 xv = __builtin_nontemporal_load(xp + idx);
    const unsigned int mb = mp[idx];
    acc = fmaxf(acc, (mb & 1u) ? xv.x : -INFINITY);
    acc = fmaxf(acc, (mb & 2u) ? xv.y : -INFINITY);
    acc = fmaxf(acc, (mb & 4u) ? xv.z : -INFINITY);
    acc = fmaxf(acc, (mb & 8u) ? xv.w : -INFINITY);
  }

  // Wave-64 shuffle max reduction.
#pragma unroll
  for (int off = 32; off > 0; off >>= 1)
    acc = fmaxf(acc, __shfl_down(acc, off));

  __shared__ float wred[TPB / 64];
  const int wave = t >> 6;
  if ((t & 63) == 0) wred[wave] = acc;
  __syncthreads();
  if (t == 0) {
    float m = fmaxf(fmaxf(wred[0], wred[1]), fmaxf(wred[2], wred[3]));
    partial[(size_t)(b * CC + c) * SS + s] = m;
  }
}

// Kernel 2: reduce SS partials per (b,c); empty mask (max == -inf) -> 0.
__global__ __launch_bounds__(TPB) void maskpool_final(
    const float* __restrict__ partial, float* __restrict__ out) {
  const int tid = blockIdx.x * blockDim.x + threadIdx.x;
  if (tid < BB * CC) {
    float m = -INFINITY;
#pragma unroll
    for (int s = 0; s < SS; ++s) m = fmaxf(m, partial[(size_t)tid * SS + s]);
    out[tid] = (m == -INFINITY) ? 0.0f : m;
  }
}

extern "C" void kernel_launch(void* const* d_in, const int* in_sizes, int n_in,
                              void* d_out, int out_size, void* d_ws,
                              size_t ws_size, hipStream_t stream) {
  const float* x = (const float*)d_in[0];
  const int* mask = (const int*)d_in[1];
  float* out = (float*)d_out;
  float* partial = (float*)d_ws;  // BB*CC*SS floats = 32 KB
  unsigned char* pm = (unsigned char*)d_ws + 32768;  // 1 MB packed mask

  const int nblk0 = GROUPS / TPB;  // 4096
  mask_pack<<<nblk0, TPB, 0, stream>>>((const int4*)mask, pm);

  const int nblk1 = BB * CC * SS;  // 8192
  maskpool_partial<<<nblk1, TPB, 0, stream>>>(x, pm, partial);

  const int nblk2 = (BB * CC + TPB - 1) / TPB;  // 4
  maskpool_final<<<nblk2, TPB, 0, stream>>>(partial, out);
}